// Round 6
// baseline (344.628 us; speedup 1.0000x reference)
//
#include <hip/hip_runtime.h>

#define V_N 5023
#define V_PAD 5120         // 80*64 vertex windows
#define KTOT 192           // 150 betas + 2 pad + 36 pose_feature + 4 pad
#define B_N 1024
#define NC_REAL 15069      // V*3
#define NCHUNK 31
#define VCHUNK 163         // 31*163 = 5053 >= 5023

// ---- ws layout, NO aliasing (end 6,818,076 <= proven-working 6,818,096) ----
#define WS_W     0          // 3*5120*192 bf16 = 5,898,240
#define WS_A2    5898240    // 1024*192 bf16   =   393,216
#define WS_RELT  6291456    // 1024*60 f32     =   245,760
#define WS_PART1 6537216    // 31*2250 f32     =   279,000
#define WS_PARTJ 6816216    // 31*15 f32       =     1,860

typedef __attribute__((ext_vector_type(8))) short bf16x8;
typedef __attribute__((ext_vector_type(4))) float f32x4;

__device__ __forceinline__ unsigned short f2bf(float f) {
  union { float f; unsigned int i; } x; x.f = f;
  unsigned int u = x.i;
  u = (u + 0x7FFFu + ((u >> 16) & 1u)) >> 16;
  return (unsigned short)u;
}

// ================= K1: fused prep =================
// blocks [0,4415): shapedirs->W k=0..149 (k-pad & v-pad rows are DON'T-CARE:
//   A2 k-pad columns are zeroed, v-pad lanes are masked in epilogue)
// blocks [4415,4651): posedirs->W k=152..187 (LDS tile transpose)
// blocks [4651,4682): JS/Jt partials, LDS-staged (16-v stages, padded stride 453)
__global__ __launch_bounds__(256) void k_prep(
    const float* __restrict__ sd, const float* __restrict__ pd,
    const float* __restrict__ jreg, const float* __restrict__ vt,
    unsigned short* __restrict__ W, float* __restrict__ part1,
    float* __restrict__ partJ) {
  __shared__ float smem[16 * 453 + 80 + 48];   // 29,440 B; reused per part
  int blk = blockIdx.x, t = threadIdx.x;
  if (blk < 4415) {
    int g = blk * 256 + t;
    if (g < NC_REAL * 75) {
      int vc = g / 75, part = g - vc * 75;
      float2 s = *(const float2*)(sd + (size_t)vc * 150 + 2 * part);
      unsigned int w = (unsigned int)f2bf(s.x) | ((unsigned int)f2bf(s.y) << 16);
      int v = vc / 3, c = vc - 3 * v;
      ((unsigned int*)W)[((size_t)c * V_PAD + v) * 96 + part] = w;
    }
  } else if (blk < 4651) {
    unsigned short* tile = (unsigned short*)smem;   // [64][38]
    int vc0 = (blk - 4415) * 64;                    // covers 15,104
    for (int i = t; i < 2304; i += 256) {           // 36 kk * 64 vc
      int kk = i >> 6, vl = i & 63;
      int vc = vc0 + vl;
      tile[vl * 38 + kk] = (vc < NC_REAL) ? f2bf(pd[(size_t)kk * NC_REAL + vc]) : (unsigned short)0;
    }
    __syncthreads();
    for (int i = t; i < 1152; i += 256) {           // 64 rows * 18 u32
      int row = i / 18, part = i - row * 18;
      int vc = vc0 + row;
      if (vc < NC_REAL) {
        int v = vc / 3, c = vc - 3 * v;
        unsigned int w = (unsigned int)tile[row * 38 + 2 * part] |
                         ((unsigned int)tile[row * 38 + 2 * part + 1] << 16);
        *((unsigned int*)(W + ((size_t)c * V_PAD + v) * KTOT + 152) + part) = w;
      }
    }
  } else {
    int chunk = blk - 4651;
    int vbase = chunk * VCHUNK;
    float* sdT = smem;                 // [16][453]  (453%32=5 -> conflict-free v-stride)
    float* jrT = smem + 16 * 453;      // [16][5]
    float* vtT = smem + 16 * 453 + 80; // [16][3]
    int c = 0, kk = 0, jj = 0, cc = 0;
    float acc[2][5] = {{0,0,0,0,0},{0,0,0,0,0}};
    float accJ = 0.f;
    if (t < 225) { c = t / 75; kk = t - c * 75; }
    else if (t >= 240) { int idx = t - 240; jj = idx / 3; cc = idx - 3 * jj; }
    for (int s0 = 0; s0 < VCHUNK; s0 += 16) {
      __syncthreads();
      int nv = VCHUNK - s0; if (nv > 16) nv = 16;
      for (int i = t; i < 7200; i += 256) {          // 16 rows * 450, coalesced
        int vl = i / 450, r = i - vl * 450;
        int v = vbase + s0 + vl;
        sdT[vl * 453 + r] = (vl < nv && v < V_N) ? sd[(size_t)v * 450 + r] : 0.f;
      }
      for (int i = t; i < 80; i += 256) {
        int vl = i / 5, j = i - vl * 5;
        int v = vbase + s0 + vl;
        jrT[vl * 5 + j] = (vl < nv && v < V_N) ? jreg[j * V_N + v] : 0.f;
      }
      for (int i = t; i < 48; i += 256) {
        int vl = i / 3, c2 = i - vl * 3;
        int v = vbase + s0 + vl;
        vtT[vl * 3 + c2] = (vl < nv && v < V_N) ? vt[v * 3 + c2] : 0.f;
      }
      __syncthreads();
      if (t < 225) {
        #pragma unroll 4
        for (int vl = 0; vl < 16; vl++) {
          float slo = sdT[vl * 453 + c * 150 + kk];
          float shi = sdT[vl * 453 + c * 150 + kk + 75];
          #pragma unroll
          for (int j = 0; j < 5; j++) {
            float jr = jrT[vl * 5 + j];
            acc[0][j] += jr * slo;
            acc[1][j] += jr * shi;
          }
        }
      } else if (t >= 240 && t < 255) {
        #pragma unroll 4
        for (int vl = 0; vl < 16; vl++)
          accJ += jrT[vl * 5 + jj] * vtT[vl * 3 + cc];
      }
    }
    if (t < 225) {
      #pragma unroll
      for (int j = 0; j < 5; j++) {
        part1[(size_t)chunk * 2250 + (j * 3 + c) * 150 + kk] = acc[0][j];
        part1[(size_t)chunk * 2250 + (j * 3 + c) * 150 + kk + 75] = acc[1][j];
      }
    } else if (t >= 240 && t < 255) {
      partJ[chunk * 15 + (t - 240)] = accJ;
    }
  }
}

// ================= K2: fused A2-pack + pose (inline js2) =================
__device__ __forceinline__ void rodrigues(const float* p, float* R) {
  float x = p[0], y = p[1], z = p[2];
  float xa = x + 1e-8f, ya = y + 1e-8f, za = z + 1e-8f;
  float angle = sqrtf(xa * xa + ya * ya + za * za);
  float inv = 1.0f / angle;
  float rx = x * inv, ry = y * inv, rz = z * inv;
  float cth = cosf(angle), s = sinf(angle), t1 = 1.0f - cth;
  float K[9] = {0.f, -rz, ry, rz, 0.f, -rx, -ry, rx, 0.f};
  float KK[9];
  #pragma unroll
  for (int i = 0; i < 3; i++)
    #pragma unroll
    for (int j = 0; j < 3; j++) {
      float a = 0.f;
      #pragma unroll
      for (int k = 0; k < 3; k++) a += K[i * 3 + k] * K[k * 3 + j];
      KK[i * 3 + j] = a;
    }
  #pragma unroll
  for (int i = 0; i < 9; i++) R[i] = s * K[i] + t1 * KK[i];
  R[0] += 1.f; R[4] += 1.f; R[8] += 1.f;
}

// blocks [0,304): A2 betas rows k=0..151 ; blocks [304,320): pose (64 batches each)
__global__ __launch_bounds__(256) void k_mid(
    const float* __restrict__ pose, const float* __restrict__ neck,
    const float* __restrict__ eye, const float* __restrict__ shp,
    const float* __restrict__ expr, const float* __restrict__ part1,
    const float* __restrict__ partJ, unsigned short* __restrict__ A2,
    float* __restrict__ relT) {
  __shared__ float sBet[150 * 64];
  __shared__ float sJS[2250];
  __shared__ float sJt[16];
  int blk = blockIdx.x, t = threadIdx.x;
  if (blk < 304) {
    int g = blk * 256 + t;                     // 304*256 = 1024*76 exact
    int b = g / 76, u = g - b * 76;            // k = 2u, 2u+1 (k<152)
    int k0 = 2 * u, k1 = 2 * u + 1;
    float f0 = 0.f, f1 = 0.f;
    if (k0 < 100) f0 = shp[b * 100 + k0]; else if (k0 < 150) f0 = expr[b * 50 + k0 - 100];
    if (k1 < 100) f1 = shp[b * 100 + k1]; else if (k1 < 150) f1 = expr[b * 50 + k1 - 100];
    unsigned int w = (unsigned int)f2bf(f0) | ((unsigned int)f2bf(f1) << 16);
    ((unsigned int*)A2)[b * 96 + u] = w;
    return;
  }
  int b0 = (blk - 304) * 64;
  for (int i = t; i < 6400; i += 256) {        // shp: 64 rows x 100, coalesced
    int row = i / 100, col = i - row * 100;
    sBet[col * 64 + row] = shp[(size_t)(b0 + row) * 100 + col];
  }
  for (int i = t; i < 3200; i += 256) {        // expr: 64 rows x 50, coalesced
    int row = i / 50, col = i - row * 50;
    sBet[(100 + col) * 64 + row] = expr[(size_t)(b0 + row) * 50 + col];
  }
  for (int i = t; i < 2250; i += 256) {        // inline js2: reduce 31 chunks
    float s = 0.f;
    #pragma unroll 4
    for (int p = 0; p < NCHUNK; p++) s += part1[(size_t)p * 2250 + i];
    sJS[i] = s;
  }
  if (t < 15) {
    float s = 0.f;
    for (int p = 0; p < NCHUNK; p++) s += partJ[p * 15 + t];
    sJt[t] = s;
  }
  __syncthreads();
  if (t >= 64) return;
  int b = b0 + t;
  float fp[15];
  fp[0] = pose[b * 6 + 0]; fp[1] = pose[b * 6 + 1]; fp[2] = pose[b * 6 + 2];
  fp[3] = neck[0]; fp[4] = neck[1]; fp[5] = neck[2];
  fp[6] = pose[b * 6 + 3]; fp[7] = pose[b * 6 + 4]; fp[8] = pose[b * 6 + 5];
  #pragma unroll
  for (int i = 0; i < 6; i++) fp[9 + i] = eye[i];
  float R[5][9];
  #pragma unroll
  for (int j = 0; j < 5; j++) rodrigues(&fp[j * 3], R[j]);
  float J[5][3];
  #pragma unroll
  for (int j = 0; j < 5; j++)
    #pragma unroll
    for (int c = 0; c < 3; c++) J[j][c] = sJt[j * 3 + c];
  for (int k = 0; k < 150; k++) {
    float be = sBet[k * 64 + t];
    #pragma unroll
    for (int j = 0; j < 5; j++)
      #pragma unroll
      for (int c = 0; c < 3; c++) J[j][c] += be * sJS[(j * 3 + c) * 150 + k];
  }
  float rel[5][3];
  #pragma unroll
  for (int c = 0; c < 3; c++) {
    rel[0][c] = J[0][c];
    rel[1][c] = J[1][c] - J[0][c];
    rel[2][c] = J[2][c] - J[1][c];
    rel[3][c] = J[3][c] - J[1][c];
    rel[4][c] = J[4][c] - J[1][c];
  }
  float GR[5][9], Gt[5][3];
  #pragma unroll
  for (int i = 0; i < 9; i++) GR[0][i] = R[0][i];
  #pragma unroll
  for (int c = 0; c < 3; c++) Gt[0][c] = rel[0][c];
  const int parent[5] = {0, 0, 1, 1, 1};
  #pragma unroll
  for (int j = 1; j < 5; j++) {
    int p = parent[j];
    #pragma unroll
    for (int r = 0; r < 3; r++)
      #pragma unroll
      for (int c = 0; c < 3; c++) {
        float a = 0.f;
        #pragma unroll
        for (int k = 0; k < 3; k++) a += GR[p][r * 3 + k] * R[j][k * 3 + c];
        GR[j][r * 3 + c] = a;
      }
    #pragma unroll
    for (int r = 0; r < 3; r++) {
      float a = Gt[p][r];
      #pragma unroll
      for (int k = 0; k < 3; k++) a += GR[p][r * 3 + k] * rel[j][k];
      Gt[j][r] = a;
    }
  }
  #pragma unroll
  for (int j = 0; j < 5; j++) {
    #pragma unroll
    for (int r = 0; r < 3; r++) {
      float a = 0.f;
      #pragma unroll
      for (int k = 0; k < 3; k++) a += GR[j][r * 3 + k] * J[j][k];
      float tr = Gt[j][r] - a;
      #pragma unroll
      for (int c = 0; c < 3; c++) relT[b * 60 + j * 12 + r * 4 + c] = GR[j][r * 3 + c];
      relT[b * 60 + j * 12 + r * 4 + 3] = tr;
    }
  }
  #pragma unroll
  for (int j = 1; j < 5; j++)
    #pragma unroll
    for (int r = 0; r < 3; r++)
      #pragma unroll
      for (int c = 0; c < 3; c++) {
        int kk = (j - 1) * 9 + r * 3 + c;
        A2[(size_t)b * KTOT + 152 + kk] = f2bf(R[j][r * 3 + c] - ((r == c) ? 1.f : 0.f));
      }
  #pragma unroll
  for (int kk = 36; kk < 40; kk++) A2[(size_t)b * KTOT + 152 + kk] = 0;
}

// ================= K3: MFMA GEMM + skinning + fused landmarks =================
// block 64b x 64v; grid (80,16) = 1280 blocks (~5/CU); 4 waves (wm,wn) 2x2,
// wave tile 32b x 32v x 3c; acc = 3*2*2 f32x4 = 48 VGPRs.
__global__ __launch_bounds__(256, 4) void k_mfma(
    const unsigned short* __restrict__ W,
    const unsigned short* __restrict__ A2,
    const float* __restrict__ relT,
    const float* __restrict__ vt,
    const float* __restrict__ lbsw,
    const int* __restrict__ land,
    float* __restrict__ out,
    float* __restrict__ outl) {
  __shared__ float sRel[64 * 60];
  __shared__ int sLand[68];
  int t = threadIdx.x;
  int wave = t >> 6, lane = t & 63, ln = lane & 15, quad = lane >> 4;
  int wm = wave >> 1, wn = wave & 1;
  int v0 = blockIdx.x * 64, b0 = blockIdx.y * 64;

  for (int i = t; i < 3840; i += 256) sRel[i] = relT[(size_t)b0 * 60 + i];
  if (t < 68) sLand[t] = land[t];

  f32x4 acc[3][2][2];
  #pragma unroll
  for (int c = 0; c < 3; c++)
    #pragma unroll
    for (int mt = 0; mt < 2; mt++)
      #pragma unroll
      for (int nt = 0; nt < 2; nt++) {
        acc[c][mt][nt].x = 0.f; acc[c][mt][nt].y = 0.f;
        acc[c][mt][nt].z = 0.f; acc[c][mt][nt].w = 0.f;
      }

  const unsigned short* Abase = A2 + (size_t)(b0 + wm * 32 + ln) * KTOT + quad * 8;
  const unsigned short* Bbase = W + (size_t)(v0 + wn * 32 + ln) * KTOT + quad * 8;

  #pragma unroll
  for (int kc = 0; kc < 6; kc++) {
    bf16x8 af0 = *(const bf16x8*)(Abase + kc * 32);
    bf16x8 af1 = *(const bf16x8*)(Abase + (size_t)16 * KTOT + kc * 32);
    #pragma unroll
    for (int c = 0; c < 3; c++)
      #pragma unroll
      for (int nt = 0; nt < 2; nt++) {
        bf16x8 bfr = *(const bf16x8*)(Bbase + ((size_t)c * V_PAD + nt * 16) * KTOT + kc * 32);
        acc[c][0][nt] = __builtin_amdgcn_mfma_f32_16x16x32_bf16(af0, bfr, acc[c][0][nt], 0, 0, 0);
        acc[c][1][nt] = __builtin_amdgcn_mfma_f32_16x16x32_bf16(af1, bfr, acc[c][1][nt], 0, 0, 0);
      }
  }
  __syncthreads();   // sRel/sLand visibility

  #pragma unroll
  for (int nt = 0; nt < 2; nt++) {
    int v = v0 + wn * 32 + nt * 16 + ln;
    bool ok = v < V_N;
    float vtx = 0.f, vty = 0.f, vtz = 0.f;
    float w5[5] = {0.f, 0.f, 0.f, 0.f, 0.f};
    if (ok) {
      vtx = vt[3 * v]; vty = vt[3 * v + 1]; vtz = vt[3 * v + 2];
      #pragma unroll
      for (int j = 0; j < 5; j++) w5[j] = lbsw[v * 5 + j];
    }
    // main vertex stores
    #pragma unroll
    for (int mt = 0; mt < 2; mt++)
      #pragma unroll
      for (int reg = 0; reg < 4; reg++) {
        int bl = wm * 32 + mt * 16 + quad * 4 + reg;
        float px = acc[0][mt][nt][reg] + vtx;
        float py = acc[1][mt][nt][reg] + vty;
        float pz = acc[2][mt][nt][reg] + vtz;
        float ox = 0.f, oy = 0.f, oz = 0.f;
        const float* M = &sRel[bl * 60];
        #pragma unroll
        for (int j = 0; j < 5; j++) {
          const float* m = M + j * 12;
          ox += w5[j] * (m[0] * px + m[1] * py + m[2] * pz + m[3]);
          oy += w5[j] * (m[4] * px + m[5] * py + m[6] * pz + m[7]);
          oz += w5[j] * (m[8] * px + m[9] * py + m[10] * pz + m[11]);
        }
        if (ok) {
          size_t off = (size_t)(b0 + bl) * NC_REAL + (size_t)3 * v;
          out[off] = ox; out[off + 1] = oy; out[off + 2] = oz;
        }
      }
    // fused landmarks: recompute for matching land indices (rare)
    for (int i = 0; i < 68; i++) {
      if (sLand[i] == v) {
        #pragma unroll
        for (int mt = 0; mt < 2; mt++)
          #pragma unroll
          for (int reg = 0; reg < 4; reg++) {
            int bl = wm * 32 + mt * 16 + quad * 4 + reg;
            float px = acc[0][mt][nt][reg] + vtx;
            float py = acc[1][mt][nt][reg] + vty;
            float pz = acc[2][mt][nt][reg] + vtz;
            float ox = 0.f, oy = 0.f, oz = 0.f;
            const float* M = &sRel[bl * 60];
            #pragma unroll
            for (int j = 0; j < 5; j++) {
              const float* m = M + j * 12;
              ox += w5[j] * (m[0] * px + m[1] * py + m[2] * pz + m[3]);
              oy += w5[j] * (m[4] * px + m[5] * py + m[6] * pz + m[7]);
              oz += w5[j] * (m[8] * px + m[9] * py + m[10] * pz + m[11]);
            }
            size_t off = ((size_t)(b0 + bl) * 68 + i) * 3;
            outl[off] = ox; outl[off + 1] = oy; outl[off + 2] = oz;
          }
      }
    }
  }
}

extern "C" void kernel_launch(void* const* d_in, const int* in_sizes, int n_in,
                              void* d_out, int out_size, void* d_ws, size_t ws_size,
                              hipStream_t stream) {
  const float* shp  = (const float*)d_in[0];
  const float* expr = (const float*)d_in[1];
  const float* pose = (const float*)d_in[2];
  const int*   land = (const int*)d_in[3];
  const float* vt   = (const float*)d_in[4];
  const float* sd   = (const float*)d_in[5];
  const float* pd   = (const float*)d_in[6];
  const float* jreg = (const float*)d_in[7];
  const float* lbsw = (const float*)d_in[8];
  const float* eye  = (const float*)d_in[9];
  const float* neck = (const float*)d_in[10];
  char* ws = (char*)d_ws;
  unsigned short* W    = (unsigned short*)(ws + WS_W);
  unsigned short* A2   = (unsigned short*)(ws + WS_A2);
  float* relT  = (float*)(ws + WS_RELT);
  float* part1 = (float*)(ws + WS_PART1);
  float* partJ = (float*)(ws + WS_PARTJ);
  float* outv = (float*)d_out;
  float* outl = outv + (size_t)B_N * NC_REAL;

  hipLaunchKernelGGL(k_prep, dim3(4682),   dim3(256), 0, stream,
                     sd, pd, jreg, vt, W, part1, partJ);
  hipLaunchKernelGGL(k_mid,  dim3(320),    dim3(256), 0, stream,
                     pose, neck, eye, shp, expr, part1, partJ, A2, relT);
  hipLaunchKernelGGL(k_mfma, dim3(80, 16), dim3(256), 0, stream,
                     W, A2, relT, vt, lbsw, land, outv, outl);
}

// Round 7
// 236.610 us; speedup vs baseline: 1.4565x; 1.4565x over previous
//
#include <hip/hip_runtime.h>

#define V_N 5023
#define V_PAD 5120         // 80*64 vertex windows
#define KTOT 192           // 150 betas + 2 pad + 36 pose_feature + 4 pad
#define B_N 1024
#define NC_REAL 15069      // V*3

// ---- ws layout, NO aliasing (end 6,546,276 <= proven-working 6,818,096) ----
#define WS_W     0          // 3*5120*192 bf16 = 5,898,240
#define WS_A2    5898240    // 1024*192 bf16   =   393,216
#define WS_RELT  6291456    // 1024*60 f32     =   245,760
#define WS_JS    6537216    // 2250 f32        =     9,000
#define WS_JT    6546216    // 15 f32          =        60

typedef __attribute__((ext_vector_type(8))) short bf16x8;
typedef __attribute__((ext_vector_type(4))) float f32x4;

__device__ __forceinline__ unsigned short f2bf(float f) {
  union { float f; unsigned int i; } x; x.f = f;
  unsigned int u = x.i;
  u = (u + 0x7FFFu + ((u >> 16) & 1u)) >> 16;
  return (unsigned short)u;
}

// ================= K1: fused prep =================
// blocks [0,99): JS/Jt via direct accumulation + atomicAdd (JS pre-zeroed by memset)
// blocks [99,4514): shapedirs->W k=0..149 (coalesced float2 -> bf16 pair)
// blocks [4514,4750): posedirs->W k=152..187 (LDS tile transpose)
__global__ __launch_bounds__(256) void k_prep(
    const float* __restrict__ sd, const float* __restrict__ pd,
    const float* __restrict__ jreg, const float* __restrict__ vt,
    unsigned short* __restrict__ W, float* __restrict__ JS,
    float* __restrict__ Jt) {
  __shared__ unsigned short tile[64 * 38];
  int blk = blockIdx.x, t = threadIdx.x;
  if (blk < 99) {
    int vs = blk * 51, ve = vs + 51; if (ve > V_N) ve = V_N;
    if (t < 150) {
      float acc[5][3];
      #pragma unroll
      for (int j = 0; j < 5; j++)
        #pragma unroll
        for (int c = 0; c < 3; c++) acc[j][c] = 0.f;
      for (int v = vs; v < ve; v++) {
        float jr[5];
        #pragma unroll
        for (int j = 0; j < 5; j++) jr[j] = jreg[j * V_N + v];
        #pragma unroll
        for (int c = 0; c < 3; c++) {
          float s = sd[(size_t)v * 450 + c * 150 + t];   // 150-lane coalesced
          #pragma unroll
          for (int j = 0; j < 5; j++) acc[j][c] += jr[j] * s;
        }
      }
      #pragma unroll
      for (int j = 0; j < 5; j++)
        #pragma unroll
        for (int c = 0; c < 3; c++)
          atomicAdd(&JS[(j * 3 + c) * 150 + t], acc[j][c]);
    } else if (t >= 160 && t < 175) {
      int j = (t - 160) / 3, c = (t - 160) % 3;
      float a = 0.f;
      for (int v = vs; v < ve; v++) a += jreg[j * V_N + v] * vt[3 * v + c];
      atomicAdd(&Jt[j * 3 + c], a);
    }
  } else if (blk < 4514) {
    int g = (blk - 99) * 256 + t;
    if (g < NC_REAL * 75) {
      int vc = g / 75, part = g - vc * 75;
      float2 s = *(const float2*)(sd + (size_t)vc * 150 + 2 * part);
      unsigned int w = (unsigned int)f2bf(s.x) | ((unsigned int)f2bf(s.y) << 16);
      int v = vc / 3, c = vc - 3 * v;
      ((unsigned int*)W)[((size_t)c * V_PAD + v) * 96 + part] = w;
    }
  } else {
    int vc0 = (blk - 4514) * 64;                    // covers 15,104
    for (int i = t; i < 2304; i += 256) {           // 36 kk * 64 vc
      int kk = i >> 6, vl = i & 63;
      int vc = vc0 + vl;
      tile[vl * 38 + kk] = (vc < NC_REAL) ? f2bf(pd[(size_t)kk * NC_REAL + vc]) : (unsigned short)0;
    }
    __syncthreads();
    for (int i = t; i < 1152; i += 256) {           // 64 rows * 18 u32
      int row = i / 18, part = i - row * 18;
      int vc = vc0 + row;
      if (vc < NC_REAL) {
        int v = vc / 3, c = vc - 3 * v;
        unsigned int w = (unsigned int)tile[row * 38 + 2 * part] |
                         ((unsigned int)tile[row * 38 + 2 * part + 1] << 16);
        *((unsigned int*)(W + ((size_t)c * V_PAD + v) * KTOT + 152) + part) = w;
      }
    }
  }
}

// ================= K2: fused A2-pack + pose =================
__device__ __forceinline__ void rodrigues(const float* p, float* R) {
  float x = p[0], y = p[1], z = p[2];
  float xa = x + 1e-8f, ya = y + 1e-8f, za = z + 1e-8f;
  float angle = sqrtf(xa * xa + ya * ya + za * za);
  float inv = 1.0f / angle;
  float rx = x * inv, ry = y * inv, rz = z * inv;
  float cth = cosf(angle), s = sinf(angle), t1 = 1.0f - cth;
  float K[9] = {0.f, -rz, ry, rz, 0.f, -rx, -ry, rx, 0.f};
  float KK[9];
  #pragma unroll
  for (int i = 0; i < 3; i++)
    #pragma unroll
    for (int j = 0; j < 3; j++) {
      float a = 0.f;
      #pragma unroll
      for (int k = 0; k < 3; k++) a += K[i * 3 + k] * K[k * 3 + j];
      KK[i * 3 + j] = a;
    }
  #pragma unroll
  for (int i = 0; i < 9; i++) R[i] = s * K[i] + t1 * KK[i];
  R[0] += 1.f; R[4] += 1.f; R[8] += 1.f;
}

// blocks [0,304): A2 betas rows k=0..151 ; blocks [304,320): pose (64 batches each)
__global__ __launch_bounds__(256) void k_mid(
    const float* __restrict__ pose, const float* __restrict__ neck,
    const float* __restrict__ eye, const float* __restrict__ shp,
    const float* __restrict__ expr, const float* __restrict__ JS,
    const float* __restrict__ Jt, unsigned short* __restrict__ A2,
    float* __restrict__ relT) {
  __shared__ float sBet[150 * 64];
  __shared__ float sJS[2250];
  __shared__ float sJt[16];
  int blk = blockIdx.x, t = threadIdx.x;
  if (blk < 304) {
    int g = blk * 256 + t;                     // 304*256 = 1024*76 exact
    int b = g / 76, u = g - b * 76;            // k = 2u, 2u+1 (k<152)
    int k0 = 2 * u, k1 = 2 * u + 1;
    float f0 = 0.f, f1 = 0.f;
    if (k0 < 100) f0 = shp[b * 100 + k0]; else if (k0 < 150) f0 = expr[b * 50 + k0 - 100];
    if (k1 < 100) f1 = shp[b * 100 + k1]; else if (k1 < 150) f1 = expr[b * 50 + k1 - 100];
    unsigned int w = (unsigned int)f2bf(f0) | ((unsigned int)f2bf(f1) << 16);
    ((unsigned int*)A2)[b * 96 + u] = w;
    return;
  }
  int b0 = (blk - 304) * 64;
  for (int i = t; i < 6400; i += 256) {        // shp: 64 rows x 100, coalesced
    int row = i / 100, col = i - row * 100;
    sBet[col * 64 + row] = shp[(size_t)(b0 + row) * 100 + col];
  }
  for (int i = t; i < 3200; i += 256) {        // expr: 64 rows x 50, coalesced
    int row = i / 50, col = i - row * 50;
    sBet[(100 + col) * 64 + row] = expr[(size_t)(b0 + row) * 50 + col];
  }
  for (int i = t; i < 2250; i += 256) sJS[i] = JS[i];
  if (t < 15) sJt[t] = Jt[t];
  __syncthreads();
  if (t >= 64) return;
  int b = b0 + t;
  float fp[15];
  fp[0] = pose[b * 6 + 0]; fp[1] = pose[b * 6 + 1]; fp[2] = pose[b * 6 + 2];
  fp[3] = neck[0]; fp[4] = neck[1]; fp[5] = neck[2];
  fp[6] = pose[b * 6 + 3]; fp[7] = pose[b * 6 + 4]; fp[8] = pose[b * 6 + 5];
  #pragma unroll
  for (int i = 0; i < 6; i++) fp[9 + i] = eye[i];
  float R[5][9];
  #pragma unroll
  for (int j = 0; j < 5; j++) rodrigues(&fp[j * 3], R[j]);
  float J[5][3];
  #pragma unroll
  for (int j = 0; j < 5; j++)
    #pragma unroll
    for (int c = 0; c < 3; c++) J[j][c] = sJt[j * 3 + c];
  for (int k = 0; k < 150; k++) {
    float be = sBet[k * 64 + t];
    #pragma unroll
    for (int j = 0; j < 5; j++)
      #pragma unroll
      for (int c = 0; c < 3; c++) J[j][c] += be * sJS[(j * 3 + c) * 150 + k];
  }
  float rel[5][3];
  #pragma unroll
  for (int c = 0; c < 3; c++) {
    rel[0][c] = J[0][c];
    rel[1][c] = J[1][c] - J[0][c];
    rel[2][c] = J[2][c] - J[1][c];
    rel[3][c] = J[3][c] - J[1][c];
    rel[4][c] = J[4][c] - J[1][c];
  }
  float GR[5][9], Gt[5][3];
  #pragma unroll
  for (int i = 0; i < 9; i++) GR[0][i] = R[0][i];
  #pragma unroll
  for (int c = 0; c < 3; c++) Gt[0][c] = rel[0][c];
  const int parent[5] = {0, 0, 1, 1, 1};
  #pragma unroll
  for (int j = 1; j < 5; j++) {
    int p = parent[j];
    #pragma unroll
    for (int r = 0; r < 3; r++)
      #pragma unroll
      for (int c = 0; c < 3; c++) {
        float a = 0.f;
        #pragma unroll
        for (int k = 0; k < 3; k++) a += GR[p][r * 3 + k] * R[j][k * 3 + c];
        GR[j][r * 3 + c] = a;
      }
    #pragma unroll
    for (int r = 0; r < 3; r++) {
      float a = Gt[p][r];
      #pragma unroll
      for (int k = 0; k < 3; k++) a += GR[p][r * 3 + k] * rel[j][k];
      Gt[j][r] = a;
    }
  }
  #pragma unroll
  for (int j = 0; j < 5; j++) {
    #pragma unroll
    for (int r = 0; r < 3; r++) {
      float a = 0.f;
      #pragma unroll
      for (int k = 0; k < 3; k++) a += GR[j][r * 3 + k] * J[j][k];
      float tr = Gt[j][r] - a;
      #pragma unroll
      for (int c = 0; c < 3; c++) relT[b * 60 + j * 12 + r * 4 + c] = GR[j][r * 3 + c];
      relT[b * 60 + j * 12 + r * 4 + 3] = tr;
    }
  }
  #pragma unroll
  for (int j = 1; j < 5; j++)
    #pragma unroll
    for (int r = 0; r < 3; r++)
      #pragma unroll
      for (int c = 0; c < 3; c++) {
        int kk = (j - 1) * 9 + r * 3 + c;
        A2[(size_t)b * KTOT + 152 + kk] = f2bf(R[j][r * 3 + c] - ((r == c) ? 1.f : 0.f));
      }
  #pragma unroll
  for (int kk = 36; kk < 40; kk++) A2[(size_t)b * KTOT + 152 + kk] = 0;
}

// ================= K3: MFMA GEMM (double-buffered LDS) + skinning + landmarks =================
// block 64b x 64v; grid (80,16); 4 waves (wm,wn) 2x2; wave tile 32b x 32v x 3c.
// LDS stride 36 shorts (72 B): 16 distinct bank bases -> minimal 2-way aliasing (free).
__global__ __launch_bounds__(256) void k_mfma(
    const unsigned short* __restrict__ W,
    const unsigned short* __restrict__ A2,
    const float* __restrict__ relT,
    const float* __restrict__ vt,
    const float* __restrict__ lbsw,
    const int* __restrict__ land,
    float* __restrict__ out,
    float* __restrict__ outl) {
  __shared__ unsigned short sA[2][64 * 36];
  __shared__ unsigned short sB[2][192 * 36];
  __shared__ float sRel[64 * 60];
  __shared__ int sLand[68];
  int t = threadIdx.x;
  int wave = t >> 6, lane = t & 63, ln = lane & 15, quad = lane >> 4;
  int wm = wave >> 1, wn = wave & 1;
  int v0 = blockIdx.x * 64, b0 = blockIdx.y * 64;

  for (int i = t; i < 3840; i += 256) sRel[i] = relT[(size_t)b0 * 60 + i];
  if (t < 68) sLand[t] = land[t];

  f32x4 acc[3][2][2];
  #pragma unroll
  for (int c = 0; c < 3; c++)
    #pragma unroll
    for (int mt = 0; mt < 2; mt++)
      #pragma unroll
      for (int nt = 0; nt < 2; nt++) {
        acc[c][mt][nt].x = 0.f; acc[c][mt][nt].y = 0.f;
        acc[c][mt][nt].z = 0.f; acc[c][mt][nt].w = 0.f;
      }

  // staging task decomposition
  int arow = t >> 2, apart = t & 3;                       // A: 64 rows x 4 parts
  const unsigned short* Asrc = A2 + (size_t)(b0 + arow) * KTOT + apart * 8;
  int brow[3], bpart[3];
  const unsigned short* Bsrc[3];
  #pragma unroll
  for (int i = 0; i < 3; i++) {
    int task = i * 256 + t;                               // B: 192 rows x 4 parts
    brow[i] = task >> 2; bpart[i] = task & 3;
    int c = brow[i] >> 6, n = brow[i] & 63;
    Bsrc[i] = W + ((size_t)c * V_PAD + v0 + n) * KTOT + bpart[i] * 8;
  }

  float4 ra, rb[3];
  ra = *(const float4*)(Asrc);                            // kc=0 prefetch
  #pragma unroll
  for (int i = 0; i < 3; i++) rb[i] = *(const float4*)(Bsrc[i]);
  *(float4*)&sA[0][arow * 36 + apart * 8] = ra;
  #pragma unroll
  for (int i = 0; i < 3; i++) *(float4*)&sB[0][brow[i] * 36 + bpart[i] * 8] = rb[i];

  #pragma unroll
  for (int kc = 0; kc < 6; kc++) {
    int cur = kc & 1, nxt = cur ^ 1;
    if (kc < 5) {                                         // prefetch kc+1 into regs
      ra = *(const float4*)(Asrc + (kc + 1) * 32);
      #pragma unroll
      for (int i = 0; i < 3; i++) rb[i] = *(const float4*)(Bsrc[i] + (kc + 1) * 32);
    }
    __syncthreads();                                      // buf[cur] visible
    bf16x8 af0 = *(const bf16x8*)&sA[cur][(wm * 32 + ln) * 36 + quad * 8];
    bf16x8 af1 = *(const bf16x8*)&sA[cur][(wm * 32 + 16 + ln) * 36 + quad * 8];
    #pragma unroll
    for (int c = 0; c < 3; c++)
      #pragma unroll
      for (int nt = 0; nt < 2; nt++) {
        bf16x8 bfr = *(const bf16x8*)&sB[cur][(c * 64 + wn * 32 + nt * 16 + ln) * 36 + quad * 8];
        acc[c][0][nt] = __builtin_amdgcn_mfma_f32_16x16x32_bf16(af0, bfr, acc[c][0][nt], 0, 0, 0);
        acc[c][1][nt] = __builtin_amdgcn_mfma_f32_16x16x32_bf16(af1, bfr, acc[c][1][nt], 0, 0, 0);
      }
    if (kc < 5) {                                         // write kc+1 into buf[nxt]
      *(float4*)&sA[nxt][arow * 36 + apart * 8] = ra;
      #pragma unroll
      for (int i = 0; i < 3; i++) *(float4*)&sB[nxt][brow[i] * 36 + bpart[i] * 8] = rb[i];
    }
  }

  #pragma unroll
  for (int nt = 0; nt < 2; nt++) {
    int v = v0 + wn * 32 + nt * 16 + ln;
    bool ok = v < V_N;
    float vtx = 0.f, vty = 0.f, vtz = 0.f;
    float w5[5] = {0.f, 0.f, 0.f, 0.f, 0.f};
    if (ok) {
      vtx = vt[3 * v]; vty = vt[3 * v + 1]; vtz = vt[3 * v + 2];
      #pragma unroll
      for (int j = 0; j < 5; j++) w5[j] = lbsw[v * 5 + j];
    }
    #pragma unroll
    for (int mt = 0; mt < 2; mt++)
      #pragma unroll
      for (int reg = 0; reg < 4; reg++) {
        int bl = wm * 32 + mt * 16 + quad * 4 + reg;
        float px = acc[0][mt][nt][reg] + vtx;
        float py = acc[1][mt][nt][reg] + vty;
        float pz = acc[2][mt][nt][reg] + vtz;
        float ox = 0.f, oy = 0.f, oz = 0.f;
        const float* M = &sRel[bl * 60];
        #pragma unroll
        for (int j = 0; j < 5; j++) {
          const float* m = M + j * 12;
          ox += w5[j] * (m[0] * px + m[1] * py + m[2] * pz + m[3]);
          oy += w5[j] * (m[4] * px + m[5] * py + m[6] * pz + m[7]);
          oz += w5[j] * (m[8] * px + m[9] * py + m[10] * pz + m[11]);
        }
        if (ok) {
          size_t off = (size_t)(b0 + bl) * NC_REAL + (size_t)3 * v;
          out[off] = ox; out[off + 1] = oy; out[off + 2] = oz;
        }
      }
    // fused landmarks: recompute for matching land indices (rare)
    for (int i = 0; i < 68; i++) {
      if (sLand[i] == v) {
        #pragma unroll
        for (int mt = 0; mt < 2; mt++)
          #pragma unroll
          for (int reg = 0; reg < 4; reg++) {
            int bl = wm * 32 + mt * 16 + quad * 4 + reg;
            float px = acc[0][mt][nt][reg] + vtx;
            float py = acc[1][mt][nt][reg] + vty;
            float pz = acc[2][mt][nt][reg] + vtz;
            float ox = 0.f, oy = 0.f, oz = 0.f;
            const float* M = &sRel[bl * 60];
            #pragma unroll
            for (int j = 0; j < 5; j++) {
              const float* m = M + j * 12;
              ox += w5[j] * (m[0] * px + m[1] * py + m[2] * pz + m[3]);
              oy += w5[j] * (m[4] * px + m[5] * py + m[6] * pz + m[7]);
              oz += w5[j] * (m[8] * px + m[9] * py + m[10] * pz + m[11]);
            }
            size_t off = ((size_t)(b0 + bl) * 68 + i) * 3;
            outl[off] = ox; outl[off + 1] = oy; outl[off + 2] = oz;
          }
      }
    }
  }
}

extern "C" void kernel_launch(void* const* d_in, const int* in_sizes, int n_in,
                              void* d_out, int out_size, void* d_ws, size_t ws_size,
                              hipStream_t stream) {
  const float* shp  = (const float*)d_in[0];
  const float* expr = (const float*)d_in[1];
  const float* pose = (const float*)d_in[2];
  const int*   land = (const int*)d_in[3];
  const float* vt   = (const float*)d_in[4];
  const float* sd   = (const float*)d_in[5];
  const float* pd   = (const float*)d_in[6];
  const float* jreg = (const float*)d_in[7];
  const float* lbsw = (const float*)d_in[8];
  const float* eye  = (const float*)d_in[9];
  const float* neck = (const float*)d_in[10];
  char* ws = (char*)d_ws;
  unsigned short* W  = (unsigned short*)(ws + WS_W);
  unsigned short* A2 = (unsigned short*)(ws + WS_A2);
  float* relT = (float*)(ws + WS_RELT);
  float* JS   = (float*)(ws + WS_JS);
  float* Jt   = (float*)(ws + WS_JT);
  float* outv = (float*)d_out;
  float* outl = outv + (size_t)B_N * NC_REAL;

  hipMemsetAsync(ws + WS_JS, 0, 9060, stream);   // zero JS + Jt for atomics
  hipLaunchKernelGGL(k_prep, dim3(4750),   dim3(256), 0, stream,
                     sd, pd, jreg, vt, W, JS, Jt);
  hipLaunchKernelGGL(k_mid,  dim3(320),    dim3(256), 0, stream,
                     pose, neck, eye, shp, expr, JS, Jt, A2, relT);
  hipLaunchKernelGGL(k_mfma, dim3(80, 16), dim3(256), 0, stream,
                     W, A2, relT, vt, lbsw, land, outv, outl);
}